// Round 10
// baseline (115.209 us; speedup 1.0000x reference)
//
#include <hip/hip_runtime.h>
#include <cstdint>
#include <cstddef>

typedef _Float16 half8 __attribute__((ext_vector_type(8)));
typedef _Float16 half4v __attribute__((ext_vector_type(4)));
typedef float f32x4 __attribute__((ext_vector_type(4)));
typedef float f32x16 __attribute__((ext_vector_type(16)));
typedef int int4v __attribute__((ext_vector_type(4)));

#define EMBD 1024
#define NHEAD 16
#define TSEQ 2048
#define NB 2
#define HD 64
#define NBH (NB*NHEAD)          // 32
#define SCK 0.18033688f         // 0.125 * log2(e)

static __device__ __forceinline__ void gload_lds16(const void* g, void* l) {
    __builtin_amdgcn_global_load_lds((const __attribute__((address_space(1))) void*)g,
                                     (__attribute__((address_space(3))) void*)l,
                                     16, 0, 0);
}

static __device__ __forceinline__ int pk2(float a, float b) {
    return __builtin_bit_cast(int, __builtin_amdgcn_cvt_pkrtz(a, b));
}

// ---------------- fp32 -> fp16 convert (x) ----------------
__global__ void k_convert_x(const float* __restrict__ x, _Float16* __restrict__ xh, int n4) {
    int i = blockIdx.x * blockDim.x + threadIdx.x;
    if (i < n4) {
        float4 v = ((const float4*)x)[i];
        half4v h;
        h.x = (_Float16)v.x; h.y = (_Float16)v.y; h.z = (_Float16)v.z; h.w = (_Float16)v.w;
        ((half4v*)xh)[i] = h;
    }
}

// ---------------- fused W transposes: fp32 [R][C] -> fp16 [C][R] ----------------
__global__ void k_prep_w(const float* __restrict__ Wa, const float* __restrict__ Wp,
                         _Float16* __restrict__ WaT, _Float16* __restrict__ WpT) {
    __shared__ float tile[32][33];
    const int bx = blockIdx.x;
    const bool isA = bx < 96;
    const float* in  = isA ? Wa : Wp;
    _Float16* out    = isA ? WaT : WpT;
    const int C      = isA ? 3072 : 1024;
    const int c0 = (isA ? bx : bx - 96) * 32, r0 = blockIdx.y * 32;
    const int tx = threadIdx.x, ty = threadIdx.y;   // 32 x 8
    #pragma unroll
    for (int j = 0; j < 4; ++j)
        tile[ty + 8*j][tx] = in[(size_t)(r0 + ty + 8*j) * C + c0 + tx];
    __syncthreads();
    #pragma unroll
    for (int j = 0; j < 4; ++j)
        out[(size_t)(c0 + ty + 8*j) * 1024 + r0 + tx] = (_Float16)tile[tx][ty + 8*j];
}

// ---------------- QKV GEMM: 128x128 tile, f16 out, K-cols pre-scaled ----------------
__global__ __launch_bounds__(256) void k_gemm_qkv(
    const _Float16* __restrict__ A,     // [4096][1024]
    const _Float16* __restrict__ Bt,    // [3072][1024]
    const float* __restrict__ bias,     // [3072]
    _Float16* __restrict__ outq)        // [4096][3072]
{
    __shared__ _Float16 As[128 * 64];
    __shared__ _Float16 Bs[128 * 64];

    const int d  = blockIdx.x;                  // 0..767
    const int wk = (d & 7) * 96 + (d >> 3);     // bijective (768 % 8 == 0)
    const int mt = wk & 31, nt = wk >> 5;       // n-major: nt = wk/32
    const int m0 = mt * 128, n0 = nt * 128;

    const int tid  = threadIdx.x;
    const int lane = tid & 63;
    const int w    = tid >> 6;
    const int wm   = w >> 1, wn = w & 1;
    const int l15  = lane & 15;
    const int lg   = lane >> 4;

    const int srow  = lane >> 3;
    const int sslot = (lane & 7) ^ srow;

    f32x4 acc[4][4];
    #pragma unroll
    for (int i = 0; i < 4; ++i)
        #pragma unroll
        for (int j = 0; j < 4; ++j)
            acc[i][j] = (f32x4){0.f, 0.f, 0.f, 0.f};

    for (int kt = 0; kt < 16; ++kt) {
        __syncthreads();
        #pragma unroll
        for (int c = 0; c < 4; ++c) {
            int r = w * 32 + c * 8 + srow;
            const _Float16* ga = A  + (size_t)(m0 + r) * 1024 + kt * 64 + sslot * 8;
            gload_lds16(ga, (char*)As + (w * 32 + c * 8) * 128);
            const _Float16* gb = Bt + (size_t)(n0 + r) * 1024 + kt * 64 + sslot * 8;
            gload_lds16(gb, (char*)Bs + (w * 32 + c * 8) * 128);
        }
        __syncthreads();

        half8 af[4][2], bf[4][2];
        #pragma unroll
        for (int mf = 0; mf < 4; ++mf) {
            int r = wm * 64 + mf * 16 + l15;
            #pragma unroll
            for (int ks = 0; ks < 2; ++ks)
                af[mf][ks] = *(const half8*)((const char*)As + r * 128 + (((ks * 4 + lg) ^ (r & 7)) * 16));
        }
        #pragma unroll
        for (int nf = 0; nf < 4; ++nf) {
            int r = wn * 64 + nf * 16 + l15;
            #pragma unroll
            for (int ks = 0; ks < 2; ++ks)
                bf[nf][ks] = *(const half8*)((const char*)Bs + r * 128 + (((ks * 4 + lg) ^ (r & 7)) * 16));
        }
        #pragma unroll
        for (int mf = 0; mf < 4; ++mf)
            #pragma unroll
            for (int nf = 0; nf < 4; ++nf) {
                acc[mf][nf] = __builtin_amdgcn_mfma_f32_16x16x32_f16(af[mf][0], bf[nf][0], acc[mf][nf], 0, 0, 0);
                acc[mf][nf] = __builtin_amdgcn_mfma_f32_16x16x32_f16(af[mf][1], bf[nf][1], acc[mf][nf], 0, 0, 0);
            }
    }

    float bv[4];
    #pragma unroll
    for (int nf = 0; nf < 4; ++nf)
        bv[nf] = bias[n0 + wn * 64 + nf * 16 + l15];
    const float osc = ((n0 >> 10) == 1) ? SCK : 1.0f;   // K block pre-scale

    #pragma unroll
    for (int mf = 0; mf < 4; ++mf) {
        #pragma unroll
        for (int j = 0; j < 4; ++j) {
            int m = m0 + wm * 64 + mf * 16 + lg * 4 + j;
            _Float16* po = outq + (size_t)m * 3072 + n0 + wn * 64 + l15;
            #pragma unroll
            for (int nf = 0; nf < 4; ++nf)
                po[nf * 16] = (_Float16)((acc[mf][nf][j] + bv[nf]) * osc);
        }
    }
}

// ---------------- proj GEMM: 64x128 tile ----------------
__global__ __launch_bounds__(256) void k_gemm_proj(
    const _Float16* __restrict__ A,     // [4096][1024] (Y)
    const _Float16* __restrict__ Bt,    // [1024][1024] (WpT)
    const float* __restrict__ bias,     // [1024]
    float* __restrict__ outf)           // [4096][1024]
{
    __shared__ _Float16 As[64 * 64];    // 8 KB
    __shared__ _Float16 Bs[128 * 64];   // 16 KB

    const int d  = blockIdx.x;                  // 0..511
    const int wk = (d & 7) * 64 + (d >> 3);     // bijective (512 % 8 == 0)
    const int mt = wk & 63, nt = wk >> 6;       // n-major
    const int m0 = mt * 64, n0 = nt * 128;

    const int tid  = threadIdx.x;
    const int lane = tid & 63;
    const int wn   = tid >> 6;                  // wave 0..3 = n-slice
    const int l15  = lane & 15;
    const int lg   = lane >> 4;

    f32x4 acc[4][2];
    #pragma unroll
    for (int i = 0; i < 4; ++i) {
        acc[i][0] = (f32x4){0.f, 0.f, 0.f, 0.f};
        acc[i][1] = (f32x4){0.f, 0.f, 0.f, 0.f};
    }

    for (int kt = 0; kt < 16; ++kt) {
        __syncthreads();
        #pragma unroll
        for (int c = 0; c < 2; ++c) {
            int s = c * 256 + tid;
            int r = s >> 3, sl = s & 7;
            const _Float16* ga = A + (size_t)(m0 + r) * 1024 + kt * 64 + ((sl ^ (r & 7)) * 8);
            gload_lds16(ga, (char*)As + s * 16);
        }
        #pragma unroll
        for (int c = 0; c < 4; ++c) {
            int s = c * 256 + tid;
            int r = s >> 3, sl = s & 7;
            const _Float16* gb = Bt + (size_t)(n0 + r) * 1024 + kt * 64 + ((sl ^ (r & 7)) * 8);
            gload_lds16(gb, (char*)Bs + s * 16);
        }
        __syncthreads();

        half8 af[4][2], bf[2][2];
        #pragma unroll
        for (int mf = 0; mf < 4; ++mf) {
            int r = mf * 16 + l15;
            #pragma unroll
            for (int ks = 0; ks < 2; ++ks)
                af[mf][ks] = *(const half8*)((const char*)As + r * 128 + (((ks * 4 + lg) ^ (r & 7)) * 16));
        }
        #pragma unroll
        for (int nf = 0; nf < 2; ++nf) {
            int r = wn * 32 + nf * 16 + l15;
            #pragma unroll
            for (int ks = 0; ks < 2; ++ks)
                bf[nf][ks] = *(const half8*)((const char*)Bs + r * 128 + (((ks * 4 + lg) ^ (r & 7)) * 16));
        }
        #pragma unroll
        for (int mf = 0; mf < 4; ++mf)
            #pragma unroll
            for (int nf = 0; nf < 2; ++nf) {
                acc[mf][nf] = __builtin_amdgcn_mfma_f32_16x16x32_f16(af[mf][0], bf[nf][0], acc[mf][nf], 0, 0, 0);
                acc[mf][nf] = __builtin_amdgcn_mfma_f32_16x16x32_f16(af[mf][1], bf[nf][1], acc[mf][nf], 0, 0, 0);
            }
    }

    float bv[2];
    bv[0] = bias[n0 + wn * 32 + l15];
    bv[1] = bias[n0 + wn * 32 + 16 + l15];

    #pragma unroll
    for (int mf = 0; mf < 4; ++mf) {
        #pragma unroll
        for (int j = 0; j < 4; ++j) {
            int m = m0 + mf * 16 + lg * 4 + j;
            float* po = outf + (size_t)m * 1024 + n0 + wn * 32 + l15;
            po[0]  = acc[mf][0][j] + bv[0];
            po[16] = acc[mf][1][j] + bv[1];
        }
    }
}

// ---------------- V transpose ----------------
// VT[bh][d][blk*128 + p] with k(p) = 16*(p>>4) + (p&3) + 8*((p>>2)&1) + 4*((p>>3)&1)
// (matches 32x32 PV A-fragment order: at (hi=p>>3&1, e=p&7), k = 16g+(e&3)+8*(e>>2)+4*hi)
__global__ __launch_bounds__(256) void k_vt(
    const _Float16* __restrict__ qkv,   // [4096][3072], V at col 2048
    _Float16* __restrict__ VT)          // [32][64][2048]
{
    __shared__ _Float16 tile[128 * 64]; // 16B slots swizzled: phys = sl ^ ((r>>4)&7)

    const int tid  = threadIdx.x;
    const int tblk = blockIdx.x;        // 0..15
    const int bh   = blockIdx.y;        // 0..31
    const int b    = bh >> 4, h = bh & 15;

    {
        const int rr = tid >> 3;        // 0..31
        const int sl = tid & 7;
        #pragma unroll
        for (int c = 0; c < 4; ++c) {
            int r = c * 32 + rr;
            int phys = sl ^ ((r >> 4) & 7);
            const _Float16* g = qkv + (size_t)(b * 2048 + tblk * 128 + r) * 3072 + 2048 + h * 64 + sl * 8;
            *(half8*)&tile[r * 64 + phys * 8] = *(const half8*)g;
        }
    }
    __syncthreads();

    const int dd = tid >> 2;            // 0..63
    const int t4 = tid & 3;             // 32-position group
    _Float16* vout = VT + ((size_t)bh * 64 + dd) * 2048 + tblk * 128 + t4 * 32;
    #pragma unroll
    for (int g = 0; g < 4; ++g) {
        half8 hv;
        #pragma unroll
        for (int e = 0; e < 8; ++e) {
            int p = t4 * 32 + g * 8 + e;
            int k = 16 * (p >> 4) + (p & 3) + 8 * ((p >> 2) & 1) + 4 * ((p >> 3) & 1);
            int phys = (dd >> 3) ^ ((k >> 4) & 7);
            hv[e] = tile[k * 64 + phys * 8 + (dd & 7)];
        }
        *(half8*)&vout[g * 8] = hv;
    }
}

// ---------------- causal flash attention, 32x32x16 MFMA ----------------
// 4 waves x 32 q-rows, QBLK=KBLK=128. Swapped QK^T (mfma(K,Q)): lane q=l31 holds
// S[q][k] with k = 32t + (reg&3)+8*(reg>>2)+4*(lane>>5). P stays in registers;
// PV A-frag for (t,half) is simply regs [8*half..8*half+7]. Row-sum fully in-lane.
__global__ __launch_bounds__(256) void k_attn(
    const _Float16* __restrict__ qkv,   // natural (Q cols 0..1023, K cols 1024..2047 pre-scaled)
    const _Float16* __restrict__ VTg,   // [bh][d][2048] kappa-permuted
    _Float16* __restrict__ Y)
{
    __shared__ _Float16 Kt[128 * 64];    // [k][d], 16B slots XOR (k&7)
    __shared__ _Float16 Vt[64 * 128];    // [d][p], 16B slots XOR (d&15)

    const int tid  = threadIdx.x;
    const int lane = tid & 63;
    const int w    = tid >> 6;           // 0..3 (q 32-row block)
    const int l31  = lane & 31;
    const int hi   = lane >> 5;
    const int bh   = blockIdx.x;
    const int by   = blockIdx.y;
    const int qt   = (by < 8) ? (15 - by) : (by - 8);
    const int b    = bh >> 4, h = bh & 15;

    // staging maps (256 threads, 4 segs each for K and V)
    int koff[4], voff[4];
    #pragma unroll
    for (int c = 0; c < 4; ++c) {
        int seg = c * 256 + tid;
        int r = seg >> 3, sl = seg & 7;
        koff[c] = r * 3072 + ((sl ^ (r & 7)) * 8);
        int d2 = seg >> 4, s16 = seg & 15;
        voff[c] = d2 * 2048 + ((s16 ^ (d2 & 15)) * 8);
    }
    const _Float16* kBase = qkv + (size_t)(b * 2048) * 3072 + 1024 + h * 64;
    const _Float16* vBase = VTg + (size_t)bh * TSEQ * HD;

    // Q regs: B-operand, lane q=l31; qb[v] elem e at d = 16v + 8hi + e
    const int qrow = qt * 128 + w * 32 + l31;
    const _Float16* qptr = qkv + (size_t)(b * 2048 + qrow) * 3072 + h * 64;
    half8 qb[4];
    #pragma unroll
    for (int v = 0; v < 4; ++v)
        qb[v] = *(const half8*)&qptr[16 * v + 8 * hi];

    f32x16 yac0, yac1;
    #pragma unroll
    for (int r = 0; r < 16; ++r) { yac0[r] = 0.f; yac1[r] = 0.f; }
    float lsum = 0.f;

    const int nkt = qt + 1;

    // prologue: tile 0 into regs
    half8 kr[4], vr[4];
    #pragma unroll
    for (int c = 0; c < 4; ++c) {
        kr[c] = *(const half8*)(kBase + koff[c]);
        vr[c] = *(const half8*)(vBase + voff[c]);
    }

    for (int kt = 0; kt < nkt; ++kt) {
        __syncthreads();
        #pragma unroll
        for (int c = 0; c < 4; ++c) {
            *(half8*)&Kt[(c * 256 + tid) * 8] = kr[c];
            *(half8*)&Vt[(c * 256 + tid) * 8] = vr[c];
        }
        if (kt + 1 < nkt) {
            const _Float16* kp = kBase + (size_t)(kt + 1) * 128 * 3072;
            const _Float16* vp = vBase + (kt + 1) * 128;
            #pragma unroll
            for (int c = 0; c < 4; ++c) {
                kr[c] = *(const half8*)(kp + koff[c]);
                vr[c] = *(const half8*)(vp + voff[c]);
            }
        }
        __syncthreads();

        const bool diag = (kt == nkt - 1);
        const int x7  = l31 & 7;
        const int x15 = l31 & 15;

        #pragma unroll
        for (int t = 0; t < 4; ++t) {
            if (diag && t > w) continue;       // fully-masked 32k block

            // QK^T: S[q=l31][k-block t], A = K rows, B = Q
            f32x16 s;
            #pragma unroll
            for (int r = 0; r < 16; ++r) s[r] = 0.f;
            __builtin_amdgcn_s_setprio(1);
            #pragma unroll
            for (int v = 0; v < 4; ++v) {
                half8 kb = *(const half8*)&Kt[(32 * t + l31) * 64 + (((2 * v + hi) ^ x7) * 8)];
                s = __builtin_amdgcn_mfma_f32_32x32x16_f16(kb, qb[v], s, 0, 0, 0);
            }
            __builtin_amdgcn_s_setprio(0);

            // P = exp2(S), mask on diagonal sub-block t==w
            if (diag && t == w) {
                const int qg = qt * 128 + w * 32 + l31;
                const int kb0 = kt * 128 + 32 * t;
                #pragma unroll
                for (int r = 0; r < 16; ++r) {
                    int kk = kb0 + (r & 3) + 8 * (r >> 2) + 4 * hi;
                    float p = (kk > qg) ? 0.f : exp2f(s[r]);
                    s[r] = p;
                    lsum += p;
                }
            } else {
                #pragma unroll
                for (int r = 0; r < 16; ++r) {
                    float p = exp2f(s[r]);
                    s[r] = p;
                    lsum += p;
                }
            }

            // PV: A-frag = regs [8*half .. 8*half+7]
            __builtin_amdgcn_s_setprio(1);
            #pragma unroll
            for (int half = 0; half < 2; ++half) {
                int4v pi;
                pi[0] = pk2(s[8 * half + 0], s[8 * half + 1]);
                pi[1] = pk2(s[8 * half + 2], s[8 * half + 3]);
                pi[2] = pk2(s[8 * half + 4], s[8 * half + 5]);
                pi[3] = pk2(s[8 * half + 6], s[8 * half + 7]);
                half8 pa = __builtin_bit_cast(half8, pi);
                int slot = 2 * (2 * t + half) + hi;
                half8 vb0 = *(const half8*)&Vt[l31 * 128        + ((slot ^ x15) * 8)];
                half8 vb1 = *(const half8*)&Vt[(32 + l31) * 128 + ((slot ^ x15) * 8)];
                yac0 = __builtin_amdgcn_mfma_f32_32x32x16_f16(pa, vb0, yac0, 0, 0, 0);
                yac1 = __builtin_amdgcn_mfma_f32_32x32x16_f16(pa, vb1, yac1, 0, 0, 0);
            }
            __builtin_amdgcn_s_setprio(0);
        }
    }

    // finalize lsum: combine the two k-half lanes, then redistribute per-reg q
    lsum += __shfl_xor(lsum, 32);

    const int trow = qt * 128 + w * 32;
    #pragma unroll
    for (int r = 0; r < 16; ++r) {
        int ql = (r & 3) + 8 * (r >> 2) + 4 * hi;      // q_local of yac row r
        float inv = 1.0f / __shfl(lsum, ql);           // lsum lives at lane q
        _Float16* po = Y + ((size_t)b * TSEQ + trow + ql) * EMBD + h * 64 + l31;
        po[0]  = (_Float16)(yac0[r] * inv);
        po[32] = (_Float16)(yac1[r] * inv);
    }
}

// ---------------- launch ----------------
extern "C" void kernel_launch(void* const* d_in, const int* in_sizes, int n_in,
                              void* d_out, int out_size, void* d_ws, size_t ws_size,
                              hipStream_t stream) {
    const float* x  = (const float*)d_in[0];
    const float* Wa = (const float*)d_in[1];
    const float* ba = (const float*)d_in[2];
    const float* Wp = (const float*)d_in[3];
    const float* bp = (const float*)d_in[4];
    float* out = (float*)d_out;

    _Float16* Xh   = (_Float16*)d_ws;                  // 4096x1024 (aliased by Yh later)
    _Float16* WaT  = Xh   + (size_t)4096 * 1024;       // 3072x1024
    _Float16* WpT  = WaT  + (size_t)3072 * 1024;       // 1024x1024
    _Float16* QKVn = WpT  + (size_t)1024 * 1024;       // 4096x3072 natural (K pre-scaled)
    _Float16* VTb  = QKVn + (size_t)4096 * 3072;       // 32x64x2048 kappa-permuted
    _Float16* Yh   = Xh;                               // alias: Xh dead after GEMM1

    k_convert_x<<<4096, 256, 0, stream>>>(x, Xh, 1048576);
    k_prep_w<<<dim3(128, 32), dim3(32, 8), 0, stream>>>(Wa, Wp, WaT, WpT);

    k_gemm_qkv<<<768, 256, 0, stream>>>(Xh, WaT, ba, QKVn);

    k_vt<<<dim3(16, NBH), 256, 0, stream>>>(QKVn, VTb);

    k_attn<<<dim3(NBH, 16), 256, 0, stream>>>(QKVn, VTb, Yh);

    k_gemm_proj<<<512, 256, 0, stream>>>(Yh, WpT, bp, out);
}

// Round 11
// 110.842 us; speedup vs baseline: 1.0394x; 1.0394x over previous
//
#include <hip/hip_runtime.h>
#include <cstdint>
#include <cstddef>

typedef _Float16 half8 __attribute__((ext_vector_type(8)));
typedef _Float16 half4v __attribute__((ext_vector_type(4)));
typedef float f32x4 __attribute__((ext_vector_type(4)));
typedef int int4v __attribute__((ext_vector_type(4)));

#define EMBD 1024
#define NHEAD 16
#define TSEQ 2048
#define NB 2
#define HD 64
#define NBH (NB*NHEAD)          // 32
#define SCK 0.18033688f         // 0.125 * log2(e)

static __device__ __forceinline__ void gload_lds16(const void* g, void* l) {
    __builtin_amdgcn_global_load_lds((const __attribute__((address_space(1))) void*)g,
                                     (__attribute__((address_space(3))) void*)l,
                                     16, 0, 0);
}

static __device__ __forceinline__ int pk2(float a, float b) {
    return __builtin_bit_cast(int, __builtin_amdgcn_cvt_pkrtz(a, b));
}

// ---------------- fp32 -> fp16 convert (x) ----------------
__global__ void k_convert_x(const float* __restrict__ x, _Float16* __restrict__ xh, int n4) {
    int i = blockIdx.x * blockDim.x + threadIdx.x;
    if (i < n4) {
        float4 v = ((const float4*)x)[i];
        half4v h;
        h.x = (_Float16)v.x; h.y = (_Float16)v.y; h.z = (_Float16)v.z; h.w = (_Float16)v.w;
        ((half4v*)xh)[i] = h;
    }
}

// ---------------- fused W transposes: fp32 [R][C] -> fp16 [C][R] ----------------
__global__ void k_prep_w(const float* __restrict__ Wa, const float* __restrict__ Wp,
                         _Float16* __restrict__ WaT, _Float16* __restrict__ WpT) {
    __shared__ float tile[32][33];
    const int bx = blockIdx.x;
    const bool isA = bx < 96;
    const float* in  = isA ? Wa : Wp;
    _Float16* out    = isA ? WaT : WpT;
    const int C      = isA ? 3072 : 1024;
    const int c0 = (isA ? bx : bx - 96) * 32, r0 = blockIdx.y * 32;
    const int tx = threadIdx.x, ty = threadIdx.y;   // 32 x 8
    #pragma unroll
    for (int j = 0; j < 4; ++j)
        tile[ty + 8*j][tx] = in[(size_t)(r0 + ty + 8*j) * C + c0 + tx];
    __syncthreads();
    #pragma unroll
    for (int j = 0; j < 4; ++j)
        out[(size_t)(c0 + ty + 8*j) * 1024 + r0 + tx] = (_Float16)tile[tx][ty + 8*j];
}

// ---------------- QKV GEMM: 128x128 tile ----------------
// Q block (n<1024):   natural f16 write.
// K block (1024..2047): natural f16 write, scaled by SCK.
// V block (n>=2048):  writes VT[bh][d][tblk*128+p] directly via LDS transpose,
//                     k(p) = 16*(2*(p>>5)+((p&7)>>2)) + 4*((p>>3)&3) + (p&3).
__global__ __launch_bounds__(256) void k_gemm_qkv(
    const _Float16* __restrict__ A,     // [4096][1024]
    const _Float16* __restrict__ Bt,    // [3072][1024]
    const float* __restrict__ bias,     // [3072]
    _Float16* __restrict__ outq,        // [4096][3072] (V region unused)
    _Float16* __restrict__ VT)          // [32][64][2048]
{
    __shared__ _Float16 smem[16512];    // staging: As=smem[0:8192), Bs=smem[8192:16384)
    _Float16* As = smem;                // epilogue (V): tile[128][129]
    _Float16* Bs = smem + 8192;

    const int d  = blockIdx.x;                  // 0..767
    const int wk = (d & 7) * 96 + (d >> 3);     // bijective (768 % 8 == 0)
    const int mt = wk & 31, nt = wk >> 5;       // n-major: nt = wk/32
    const int m0 = mt * 128, n0 = nt * 128;

    const int tid  = threadIdx.x;
    const int lane = tid & 63;
    const int w    = tid >> 6;
    const int wm   = w >> 1, wn = w & 1;
    const int l15  = lane & 15;
    const int lg   = lane >> 4;

    const int srow  = lane >> 3;
    const int sslot = (lane & 7) ^ srow;

    f32x4 acc[4][4];
    #pragma unroll
    for (int i = 0; i < 4; ++i)
        #pragma unroll
        for (int j = 0; j < 4; ++j)
            acc[i][j] = (f32x4){0.f, 0.f, 0.f, 0.f};

    for (int kt = 0; kt < 16; ++kt) {
        __syncthreads();
        #pragma unroll
        for (int c = 0; c < 4; ++c) {
            int r = w * 32 + c * 8 + srow;
            const _Float16* ga = A  + (size_t)(m0 + r) * 1024 + kt * 64 + sslot * 8;
            gload_lds16(ga, (char*)As + (w * 32 + c * 8) * 128);
            const _Float16* gb = Bt + (size_t)(n0 + r) * 1024 + kt * 64 + sslot * 8;
            gload_lds16(gb, (char*)Bs + (w * 32 + c * 8) * 128);
        }
        __syncthreads();

        half8 af[4][2], bf[4][2];
        #pragma unroll
        for (int mf = 0; mf < 4; ++mf) {
            int r = wm * 64 + mf * 16 + l15;
            #pragma unroll
            for (int ks = 0; ks < 2; ++ks)
                af[mf][ks] = *(const half8*)((const char*)As + r * 128 + (((ks * 4 + lg) ^ (r & 7)) * 16));
        }
        #pragma unroll
        for (int nf = 0; nf < 4; ++nf) {
            int r = wn * 64 + nf * 16 + l15;
            #pragma unroll
            for (int ks = 0; ks < 2; ++ks)
                bf[nf][ks] = *(const half8*)((const char*)Bs + r * 128 + (((ks * 4 + lg) ^ (r & 7)) * 16));
        }
        #pragma unroll
        for (int mf = 0; mf < 4; ++mf)
            #pragma unroll
            for (int nf = 0; nf < 4; ++nf) {
                acc[mf][nf] = __builtin_amdgcn_mfma_f32_16x16x32_f16(af[mf][0], bf[nf][0], acc[mf][nf], 0, 0, 0);
                acc[mf][nf] = __builtin_amdgcn_mfma_f32_16x16x32_f16(af[mf][1], bf[nf][1], acc[mf][nf], 0, 0, 0);
            }
    }

    float bv[4];
    #pragma unroll
    for (int nf = 0; nf < 4; ++nf)
        bv[nf] = bias[n0 + wn * 64 + nf * 16 + l15];

    const int which = n0 >> 10;         // 0=Q, 1=K, 2=V
    if (which < 2) {
        const float osc = (which == 1) ? SCK : 1.0f;
        #pragma unroll
        for (int mf = 0; mf < 4; ++mf) {
            #pragma unroll
            for (int j = 0; j < 4; ++j) {
                int m = m0 + wm * 64 + mf * 16 + lg * 4 + j;
                _Float16* po = outq + (size_t)m * 3072 + n0 + wn * 64 + l15;
                #pragma unroll
                for (int nf = 0; nf < 4; ++nf)
                    po[nf * 16] = (_Float16)((acc[mf][nf][j] + bv[nf]) * osc);
            }
        }
    } else {
        // ---- V: transpose through LDS, write VT directly ----
        __syncthreads();                       // all waves done with As/Bs fragments
        #pragma unroll
        for (int mf = 0; mf < 4; ++mf)
            #pragma unroll
            for (int j = 0; j < 4; ++j) {
                int m = wm * 64 + mf * 16 + lg * 4 + j;       // t_local
                #pragma unroll
                for (int nf = 0; nf < 4; ++nf) {
                    int n = wn * 64 + nf * 16 + l15;          // hd index
                    smem[m * 129 + n] = (_Float16)(acc[mf][nf][j] + bv[nf]);
                }
            }
        __syncthreads();

        const int b     = m0 >> 11;
        const int h0    = (n0 - 2048) >> 6;    // first head of this n-tile
        const int tloc0 = m0 & 2047;           // 128-aligned t base
        #pragma unroll
        for (int c = 0; c < 8; ++c) {
            int seg = c * 256 + tid;           // 0..2047
            int hd  = seg >> 4;                // 0..127 (h_local*64 + d)
            int s   = seg & 15;                // 16B segment within row
            half8 hv8;
            #pragma unroll
            for (int e = 0; e < 8; ++e) {
                int p = s * 8 + e;
                int k = 16 * (2 * (p >> 5) + ((p & 7) >> 2)) + 4 * ((p >> 3) & 3) + (p & 3);
                hv8[e] = smem[k * 129 + hd];
            }
            size_t row = (size_t)(b * 16 + h0 + (hd >> 6)) * 64 + (hd & 63);
            *(half8*)&VT[row * 2048 + tloc0 + s * 8] = hv8;
        }
    }
}

// ---------------- proj GEMM: 64x128 tile ----------------
__global__ __launch_bounds__(256) void k_gemm_proj(
    const _Float16* __restrict__ A,     // [4096][1024] (Y)
    const _Float16* __restrict__ Bt,    // [1024][1024] (WpT)
    const float* __restrict__ bias,     // [1024]
    float* __restrict__ outf)           // [4096][1024]
{
    __shared__ _Float16 As[64 * 64];    // 8 KB
    __shared__ _Float16 Bs[128 * 64];   // 16 KB

    const int d  = blockIdx.x;                  // 0..511
    const int wk = (d & 7) * 64 + (d >> 3);     // bijective (512 % 8 == 0)
    const int mt = wk & 63, nt = wk >> 6;       // n-major
    const int m0 = mt * 64, n0 = nt * 128;

    const int tid  = threadIdx.x;
    const int lane = tid & 63;
    const int wn   = tid >> 6;                  // wave 0..3 = n-slice
    const int l15  = lane & 15;
    const int lg   = lane >> 4;

    f32x4 acc[4][2];
    #pragma unroll
    for (int i = 0; i < 4; ++i) {
        acc[i][0] = (f32x4){0.f, 0.f, 0.f, 0.f};
        acc[i][1] = (f32x4){0.f, 0.f, 0.f, 0.f};
    }

    for (int kt = 0; kt < 16; ++kt) {
        __syncthreads();
        #pragma unroll
        for (int c = 0; c < 2; ++c) {
            int s = c * 256 + tid;
            int r = s >> 3, sl = s & 7;
            const _Float16* ga = A + (size_t)(m0 + r) * 1024 + kt * 64 + ((sl ^ (r & 7)) * 8);
            gload_lds16(ga, (char*)As + s * 16);
        }
        #pragma unroll
        for (int c = 0; c < 4; ++c) {
            int s = c * 256 + tid;
            int r = s >> 3, sl = s & 7;
            const _Float16* gb = Bt + (size_t)(n0 + r) * 1024 + kt * 64 + ((sl ^ (r & 7)) * 8);
            gload_lds16(gb, (char*)Bs + s * 16);
        }
        __syncthreads();

        half8 af[4][2], bf[2][2];
        #pragma unroll
        for (int mf = 0; mf < 4; ++mf) {
            int r = mf * 16 + l15;
            #pragma unroll
            for (int ks = 0; ks < 2; ++ks)
                af[mf][ks] = *(const half8*)((const char*)As + r * 128 + (((ks * 4 + lg) ^ (r & 7)) * 16));
        }
        #pragma unroll
        for (int nf = 0; nf < 2; ++nf) {
            int r = wn * 32 + nf * 16 + l15;
            #pragma unroll
            for (int ks = 0; ks < 2; ++ks)
                bf[nf][ks] = *(const half8*)((const char*)Bs + r * 128 + (((ks * 4 + lg) ^ (r & 7)) * 16));
        }
        #pragma unroll
        for (int mf = 0; mf < 4; ++mf)
            #pragma unroll
            for (int nf = 0; nf < 2; ++nf) {
                acc[mf][nf] = __builtin_amdgcn_mfma_f32_16x16x32_f16(af[mf][0], bf[nf][0], acc[mf][nf], 0, 0, 0);
                acc[mf][nf] = __builtin_amdgcn_mfma_f32_16x16x32_f16(af[mf][1], bf[nf][1], acc[mf][nf], 0, 0, 0);
            }
    }

    float bv[2];
    bv[0] = bias[n0 + wn * 32 + l15];
    bv[1] = bias[n0 + wn * 32 + 16 + l15];

    #pragma unroll
    for (int mf = 0; mf < 4; ++mf) {
        #pragma unroll
        for (int j = 0; j < 4; ++j) {
            int m = m0 + mf * 16 + lg * 4 + j;
            float* po = outf + (size_t)m * 1024 + n0 + wn * 32 + l15;
            po[0]  = acc[mf][0][j] + bv[0];
            po[16] = acc[mf][1][j] + bv[1];
        }
    }
}

// ---------------- causal flash attention (R8 structure: 16x16, 8 waves, reg-P) ----------------
__global__ __launch_bounds__(512) void k_attn(
    const _Float16* __restrict__ qkv,   // natural (Q cols 0..1023, K cols 1024..2047 pre-scaled)
    const _Float16* __restrict__ VTg,   // [bh][d][2048] kappa-permuted
    _Float16* __restrict__ Y)
{
    __shared__ _Float16 Kt[128 * 64];    // [k][d], 16B slots XOR (k&7)
    __shared__ _Float16 Vt[64 * 128];    // [d][p], 16B slots XOR (d&15)

    const int tid  = threadIdx.x;
    const int lane = tid & 63;
    const int w    = tid >> 6;           // 0..7 (q-row block)
    const int l15  = lane & 15;
    const int lg   = lane >> 4;
    const int bh   = blockIdx.x;
    const int by   = blockIdx.y;
    const int qt   = (by < 8) ? (15 - by) : (by - 8);   // pairs sum to 17 tiles
    const int b    = bh >> 4, h = bh & 15;

    // staging maps: LDS dest linear tid*16B, global src pre-swizzled
    const int rA  = tid >> 3;            // 0..63  (K rows; +64 second half)
    const int slA = tid & 7;
    const size_t kOffA = (size_t)rA * 3072 + ((slA ^ (rA & 7)) * 8);
    const _Float16* kBase = qkv + (size_t)(b * 2048) * 3072 + 1024 + h * 64;

    const int dA = tid >> 4;             // 0..31  (V d-rows; +32 second half)
    const int sA = tid & 15;
    const size_t vOffA = (size_t)dA * 2048 + ((sA ^ (dA & 15)) * 8);
    const _Float16* vBase = VTg + (size_t)bh * TSEQ * HD;

    const int x7   = l15 & 7;
    const int kph0 = (lg ^ x7) * 8;
    const int kph1 = ((4 + lg) ^ x7) * 8;

    const int qrow = qt * 128 + w * 16 + l15;
    const _Float16* qptr = qkv + (size_t)(b * 2048 + qrow) * 3072 + h * 64;
    half8 qa0 = *(const half8*)&qptr[lg * 8];
    half8 qa1 = *(const half8*)&qptr[32 + lg * 8];

    half8 ones;
    #pragma unroll
    for (int i = 0; i < 8; ++i) ones[i] = (_Float16)1.0f;

    f32x4 yac[4];
    #pragma unroll
    for (int nf = 0; nf < 4; ++nf) yac[nf] = (f32x4){0.f, 0.f, 0.f, 0.f};
    f32x4 lsum = (f32x4){0.f, 0.f, 0.f, 0.f};

    const int nkt = qt + 1;

    // prologue: tile 0 into regs
    half8 kra = *(const half8*)(kBase + kOffA);
    half8 krb = *(const half8*)(kBase + kOffA + (size_t)64 * 3072);
    half8 vra = *(const half8*)(vBase + vOffA);
    half8 vrb = *(const half8*)(vBase + vOffA + 32 * 2048);

    for (int kt = 0; kt < nkt; ++kt) {
        __syncthreads();                       // consumers of kt-1 done
        *(half8*)&Kt[tid * 8]        = kra;
        *(half8*)&Kt[4096 + tid * 8] = krb;
        *(half8*)&Vt[tid * 8]        = vra;
        *(half8*)&Vt[4096 + tid * 8] = vrb;
        if (kt + 1 < nkt) {                    // next-tile loads fly under compute
            const _Float16* kp = kBase + (size_t)(kt + 1) * 128 * 3072;
            kra = *(const half8*)(kp + kOffA);
            krb = *(const half8*)(kp + kOffA + (size_t)64 * 3072);
            const _Float16* vp = vBase + (kt + 1) * 128;
            vra = *(const half8*)(vp + vOffA);
            vrb = *(const half8*)(vp + vOffA + 32 * 2048);
        }
        __syncthreads();                       // staged tile visible

        const bool diag = (kt == nkt - 1);

        // S^T = K Q^T : lane (q=l15, lg) holds S[q][k], k = 16f + 4lg + j
        f32x4 s[8];
        __builtin_amdgcn_s_setprio(1);
        #pragma unroll
        for (int f = 0; f < 8; ++f) {
            if (diag && f > w) { s[f] = (f32x4){0.f, 0.f, 0.f, 0.f}; continue; }
            int rr = f * 16 + l15;
            half8 kb0 = *(const half8*)&Kt[rr * 64 + kph0];
            half8 kb1 = *(const half8*)&Kt[rr * 64 + kph1];
            f32x4 z = (f32x4){0.f, 0.f, 0.f, 0.f};
            z = __builtin_amdgcn_mfma_f32_16x16x32_f16(kb0, qa0, z, 0, 0, 0);
            z = __builtin_amdgcn_mfma_f32_16x16x32_f16(kb1, qa1, z, 0, 0, 0);
            s[f] = z;
        }
        __builtin_amdgcn_s_setprio(0);

        // P = exp2(S) (K pre-scaled); causal mask on diagonal tile -> exact 0
        if (diag) {
            const int qg = qt * 128 + w * 16 + l15;
            #pragma unroll
            for (int f = 0; f < 8; ++f) {
                if (f > w) continue;           // already zero
                #pragma unroll
                for (int j = 0; j < 4; ++j) {
                    int kk = kt * 128 + 16 * f + 4 * lg + j;
                    s[f][j] = (kk > qg) ? 0.f : exp2f(s[f][j]);
                }
            }
        } else {
            #pragma unroll
            for (int f = 0; f < 8; ++f)
                #pragma unroll
                for (int j = 0; j < 4; ++j) s[f][j] = exp2f(s[f][j]);
        }

        // PV: pack P in-register into A-fragments (k-order matches VT's kappa)
        __builtin_amdgcn_s_setprio(1);
        #pragma unroll
        for (int t = 0; t < 4; ++t) {
            int4v pi;
            pi[0] = pk2(s[2 * t][0],     s[2 * t][1]);
            pi[1] = pk2(s[2 * t][2],     s[2 * t][3]);
            pi[2] = pk2(s[2 * t + 1][0], s[2 * t + 1][1]);
            pi[3] = pk2(s[2 * t + 1][2], s[2 * t + 1][3]);
            half8 pa = __builtin_bit_cast(half8, pi);
            lsum = __builtin_amdgcn_mfma_f32_16x16x32_f16(pa, ones, lsum, 0, 0, 0);
            #pragma unroll
            for (int nf = 0; nf < 4; ++nf) {
                half8 vb = *(const half8*)&Vt[(nf * 16 + l15) * 128 + (((t * 4 + lg) ^ l15) * 8)];
                yac[nf] = __builtin_amdgcn_mfma_f32_16x16x32_f16(pa, vb, yac[nf], 0, 0, 0);
            }
        }
        __builtin_amdgcn_s_setprio(0);
    }

    // normalize + store Y (token-major): yac row = q (lg*4+j), col = d (nf*16+l15)
    const int trow = qt * 128 + w * 16 + lg * 4;
    #pragma unroll
    for (int j = 0; j < 4; ++j) {
        float inv = 1.f / lsum[j];
        #pragma unroll
        for (int nf = 0; nf < 4; ++nf) {
            float yv = yac[nf][j] * inv;
            Y[((size_t)b * TSEQ + trow + j) * EMBD + h * 64 + nf * 16 + l15] = (_Float16)yv;
        }
    }
}

// ---------------- launch ----------------
extern "C" void kernel_launch(void* const* d_in, const int* in_sizes, int n_in,
                              void* d_out, int out_size, void* d_ws, size_t ws_size,
                              hipStream_t stream) {
    const float* x  = (const float*)d_in[0];
    const float* Wa = (const float*)d_in[1];
    const float* ba = (const float*)d_in[2];
    const float* Wp = (const float*)d_in[3];
    const float* bp = (const float*)d_in[4];
    float* out = (float*)d_out;

    _Float16* Xh   = (_Float16*)d_ws;                  // 4096x1024 (aliased by Yh later)
    _Float16* WaT  = Xh   + (size_t)4096 * 1024;       // 3072x1024
    _Float16* WpT  = WaT  + (size_t)3072 * 1024;       // 1024x1024
    _Float16* QKVn = WpT  + (size_t)1024 * 1024;       // 4096x3072 (V region unused)
    _Float16* VTb  = QKVn + (size_t)4096 * 3072;       // 32x64x2048 kappa-permuted
    _Float16* Yh   = Xh;                               // alias: Xh dead after GEMM1

    k_convert_x<<<4096, 256, 0, stream>>>(x, Xh, 1048576);
    k_prep_w<<<dim3(128, 32), dim3(32, 8), 0, stream>>>(Wa, Wp, WaT, WpT);

    k_gemm_qkv<<<768, 256, 0, stream>>>(Xh, WaT, ba, QKVn, VTb);

    k_attn<<<dim3(NBH, 16), 512, 0, stream>>>(QKVn, VTb, Yh);

    k_gemm_proj<<<512, 256, 0, stream>>>(Yh, WpT, bp, out);
}

// Round 12
// 97.037 us; speedup vs baseline: 1.1873x; 1.1423x over previous
//
#include <hip/hip_runtime.h>
#include <cstdint>
#include <cstddef>

typedef _Float16 half8 __attribute__((ext_vector_type(8)));
typedef _Float16 half4v __attribute__((ext_vector_type(4)));
typedef float f32x4 __attribute__((ext_vector_type(4)));
typedef int int4v __attribute__((ext_vector_type(4)));

#define EMBD 1024
#define NHEAD 16
#define TSEQ 2048
#define NB 2
#define HD 64
#define NBH (NB*NHEAD)          // 32
#define SCK 0.18033688f         // 0.125 * log2(e)

static __device__ __forceinline__ void gload_lds16(const void* g, void* l) {
    __builtin_amdgcn_global_load_lds((const __attribute__((address_space(1))) void*)g,
                                     (__attribute__((address_space(3))) void*)l,
                                     16, 0, 0);
}

static __device__ __forceinline__ int pk2(float a, float b) {
    return __builtin_bit_cast(int, __builtin_amdgcn_cvt_pkrtz(a, b));
}

// ---------------- fused prep: x fp32->fp16 convert + both W transposes ----------------
// bx < 4096: convert 256 float4 of x.  bx >= 4096: 32x32 transpose tile of Wa/Wp.
__global__ __launch_bounds__(256) void k_prep(
    const float* __restrict__ x,  _Float16* __restrict__ xh,
    const float* __restrict__ Wa, const float* __restrict__ Wp,
    _Float16* __restrict__ WaT,   _Float16* __restrict__ WpT)
{
    const int bx = blockIdx.x;
    if (bx < 4096) {
        int i = bx * 256 + threadIdx.x;
        float4 v = ((const float4*)x)[i];
        half4v h;
        h.x = (_Float16)v.x; h.y = (_Float16)v.y; h.z = (_Float16)v.z; h.w = (_Float16)v.w;
        ((half4v*)xh)[i] = h;
        return;
    }
    __shared__ float tile[32][33];
    const int idx = bx - 4096;          // 0..4095
    const int bxx = idx & 127;          // 0..127 (96 Wa + 32 Wp)
    const int byy = idx >> 7;           // 0..31
    const bool isA = bxx < 96;
    const float* in  = isA ? Wa : Wp;
    _Float16* out    = isA ? WaT : WpT;
    const int C      = isA ? 3072 : 1024;
    const int c0 = (isA ? bxx : bxx - 96) * 32, r0 = byy * 32;
    const int tx = threadIdx.x & 31, ty = threadIdx.x >> 5;   // 32 x 8
    #pragma unroll
    for (int j = 0; j < 4; ++j)
        tile[ty + 8*j][tx] = in[(size_t)(r0 + ty + 8*j) * C + c0 + tx];
    __syncthreads();
    #pragma unroll
    for (int j = 0; j < 4; ++j)
        out[(size_t)(c0 + ty + 8*j) * 1024 + r0 + tx] = (_Float16)tile[tx][ty + 8*j];
}

// ---------------- QKV GEMM: 128x64 tile (1536 blocks -> ~6/CU) ----------------
// n-tile = 64 = one head-column. Q (n<1024): natural f16. K (1024..2047): natural*SCK.
// V (n>=2048): transpose through LDS, write VT[bh][d][tloc+p] directly,
//              k(p) = 16*(2*(p>>5)+((p&7)>>2)) + 4*((p>>3)&3) + (p&3).
__global__ __launch_bounds__(256) void k_gemm_qkv(
    const _Float16* __restrict__ A,     // [4096][1024]
    const _Float16* __restrict__ Bt,    // [3072][1024]
    const float* __restrict__ bias,     // [3072]
    _Float16* __restrict__ outq,        // [4096][3072] (V region unused)
    _Float16* __restrict__ VT)          // [32][64][2048]
{
    __shared__ _Float16 smem[12288];    // As[0:8192) 128x64, Bs[8192:12288) 64x64
    _Float16* As = smem;
    _Float16* Bs = smem + 8192;

    // 2D XCD chunking: xcd = d&7 -> (mchunk 0..3, nchunk 0..1); 8 m x 24 n per XCD
    const int d    = blockIdx.x;               // 0..1535
    const int xcd  = d & 7;
    const int idx  = d >> 3;                   // 0..191
    const int mt   = (xcd >> 1) * 8  + (idx & 7);
    const int ntl  = (xcd &  1) * 24 + (idx >> 3);
    const int m0 = mt * 128, n0 = ntl * 64;

    const int tid  = threadIdx.x;
    const int lane = tid & 63;
    const int w    = tid >> 6;
    const int wm   = w >> 1, wn = w & 1;       // wave: 64m x 32n
    const int l15  = lane & 15;
    const int lg   = lane >> 4;

    f32x4 acc[4][2];
    #pragma unroll
    for (int i = 0; i < 4; ++i) {
        acc[i][0] = (f32x4){0.f, 0.f, 0.f, 0.f};
        acc[i][1] = (f32x4){0.f, 0.f, 0.f, 0.f};
    }

    for (int kt = 0; kt < 16; ++kt) {
        __syncthreads();
        #pragma unroll
        for (int c = 0; c < 4; ++c) {          // A: 1024 segs
            int s = c * 256 + tid;
            int r = s >> 3, sl = s & 7;
            const _Float16* ga = A + (size_t)(m0 + r) * 1024 + kt * 64 + ((sl ^ (r & 7)) * 8);
            gload_lds16(ga, (char*)As + s * 16);
        }
        #pragma unroll
        for (int c = 0; c < 2; ++c) {          // B: 512 segs
            int s = c * 256 + tid;
            int r = s >> 3, sl = s & 7;
            const _Float16* gb = Bt + (size_t)(n0 + r) * 1024 + kt * 64 + ((sl ^ (r & 7)) * 8);
            gload_lds16(gb, (char*)Bs + s * 16);
        }
        __syncthreads();

        half8 af[4][2], bf[2][2];
        #pragma unroll
        for (int mf = 0; mf < 4; ++mf) {
            int r = wm * 64 + mf * 16 + l15;
            #pragma unroll
            for (int ks = 0; ks < 2; ++ks)
                af[mf][ks] = *(const half8*)((const char*)As + r * 128 + (((ks * 4 + lg) ^ (r & 7)) * 16));
        }
        #pragma unroll
        for (int nf = 0; nf < 2; ++nf) {
            int r = wn * 32 + nf * 16 + l15;
            #pragma unroll
            for (int ks = 0; ks < 2; ++ks)
                bf[nf][ks] = *(const half8*)((const char*)Bs + r * 128 + (((ks * 4 + lg) ^ (r & 7)) * 16));
        }
        #pragma unroll
        for (int mf = 0; mf < 4; ++mf)
            #pragma unroll
            for (int nf = 0; nf < 2; ++nf) {
                acc[mf][nf] = __builtin_amdgcn_mfma_f32_16x16x32_f16(af[mf][0], bf[nf][0], acc[mf][nf], 0, 0, 0);
                acc[mf][nf] = __builtin_amdgcn_mfma_f32_16x16x32_f16(af[mf][1], bf[nf][1], acc[mf][nf], 0, 0, 0);
            }
    }

    float bv[2];
    bv[0] = bias[n0 + wn * 32 + l15];
    bv[1] = bias[n0 + wn * 32 + 16 + l15];

    const int which = n0 >> 10;         // 0=Q, 1=K, 2=V
    if (which < 2) {
        const float osc = (which == 1) ? SCK : 1.0f;
        #pragma unroll
        for (int mf = 0; mf < 4; ++mf) {
            #pragma unroll
            for (int j = 0; j < 4; ++j) {
                int m = m0 + wm * 64 + mf * 16 + lg * 4 + j;
                _Float16* po = outq + (size_t)m * 3072 + n0 + wn * 32 + l15;
                po[0]  = (_Float16)((acc[mf][0][j] + bv[0]) * osc);
                po[16] = (_Float16)((acc[mf][1][j] + bv[1]) * osc);
            }
        }
    } else {
        // ---- V: transpose through LDS (tile[128 t][65-stride d]), write VT ----
        __syncthreads();                       // staging reads done
        #pragma unroll
        for (int mf = 0; mf < 4; ++mf)
            #pragma unroll
            for (int j = 0; j < 4; ++j) {
                int m = wm * 64 + mf * 16 + lg * 4 + j;       // t_local
                smem[m * 65 + wn * 32 + l15]      = (_Float16)(acc[mf][0][j] + bv[0]);
                smem[m * 65 + wn * 32 + 16 + l15] = (_Float16)(acc[mf][1][j] + bv[1]);
            }
        __syncthreads();

        const int b     = m0 >> 11;
        const int h     = (n0 - 2048) >> 6;    // head of this n-tile
        const int tloc0 = m0 & 2047;
        _Float16* vbase = VT + ((size_t)(b * 16 + h) * 64) * 2048 + tloc0;
        #pragma unroll
        for (int c = 0; c < 4; ++c) {
            int seg = c * 256 + tid;           // 0..1023
            int dd  = seg >> 4;                // 0..63
            int s   = seg & 15;                // 16B segment
            half8 hv8;
            #pragma unroll
            for (int e = 0; e < 8; ++e) {
                int p = s * 8 + e;
                int k = 16 * (2 * (p >> 5) + ((p & 7) >> 2)) + 4 * ((p >> 3) & 3) + (p & 3);
                hv8[e] = smem[k * 65 + dd];
            }
            *(half8*)&vbase[(size_t)dd * 2048 + s * 8] = hv8;
        }
    }
}

// ---------------- proj GEMM: 64x128 tile, 2D XCD chunks ----------------
__global__ __launch_bounds__(256) void k_gemm_proj(
    const _Float16* __restrict__ A,     // [4096][1024] (Y)
    const _Float16* __restrict__ Bt,    // [1024][1024] (WpT)
    const float* __restrict__ bias,     // [1024]
    float* __restrict__ outf)           // [4096][1024]
{
    __shared__ _Float16 As[64 * 64];    // 8 KB
    __shared__ _Float16 Bs[128 * 64];   // 16 KB

    // 2D XCD chunking: 16 m x 4 n per XCD
    const int d   = blockIdx.x;                 // 0..511
    const int xcd = d & 7;
    const int idx = d >> 3;                     // 0..63
    const int mt  = (xcd >> 1) * 16 + (idx & 15);
    const int nt  = (xcd &  1) * 4  + (idx >> 4);
    const int m0 = mt * 64, n0 = nt * 128;

    const int tid  = threadIdx.x;
    const int lane = tid & 63;
    const int wn   = tid >> 6;                  // wave 0..3 = n-slice
    const int l15  = lane & 15;
    const int lg   = lane >> 4;

    f32x4 acc[4][2];
    #pragma unroll
    for (int i = 0; i < 4; ++i) {
        acc[i][0] = (f32x4){0.f, 0.f, 0.f, 0.f};
        acc[i][1] = (f32x4){0.f, 0.f, 0.f, 0.f};
    }

    for (int kt = 0; kt < 16; ++kt) {
        __syncthreads();
        #pragma unroll
        for (int c = 0; c < 2; ++c) {
            int s = c * 256 + tid;
            int r = s >> 3, sl = s & 7;
            const _Float16* ga = A + (size_t)(m0 + r) * 1024 + kt * 64 + ((sl ^ (r & 7)) * 8);
            gload_lds16(ga, (char*)As + s * 16);
        }
        #pragma unroll
        for (int c = 0; c < 4; ++c) {
            int s = c * 256 + tid;
            int r = s >> 3, sl = s & 7;
            const _Float16* gb = Bt + (size_t)(n0 + r) * 1024 + kt * 64 + ((sl ^ (r & 7)) * 8);
            gload_lds16(gb, (char*)Bs + s * 16);
        }
        __syncthreads();

        half8 af[4][2], bf[2][2];
        #pragma unroll
        for (int mf = 0; mf < 4; ++mf) {
            int r = mf * 16 + l15;
            #pragma unroll
            for (int ks = 0; ks < 2; ++ks)
                af[mf][ks] = *(const half8*)((const char*)As + r * 128 + (((ks * 4 + lg) ^ (r & 7)) * 16));
        }
        #pragma unroll
        for (int nf = 0; nf < 2; ++nf) {
            int r = wn * 32 + nf * 16 + l15;
            #pragma unroll
            for (int ks = 0; ks < 2; ++ks)
                bf[nf][ks] = *(const half8*)((const char*)Bs + r * 128 + (((ks * 4 + lg) ^ (r & 7)) * 16));
        }
        #pragma unroll
        for (int mf = 0; mf < 4; ++mf)
            #pragma unroll
            for (int nf = 0; nf < 2; ++nf) {
                acc[mf][nf] = __builtin_amdgcn_mfma_f32_16x16x32_f16(af[mf][0], bf[nf][0], acc[mf][nf], 0, 0, 0);
                acc[mf][nf] = __builtin_amdgcn_mfma_f32_16x16x32_f16(af[mf][1], bf[nf][1], acc[mf][nf], 0, 0, 0);
            }
    }

    float bv[2];
    bv[0] = bias[n0 + wn * 32 + l15];
    bv[1] = bias[n0 + wn * 32 + 16 + l15];

    #pragma unroll
    for (int mf = 0; mf < 4; ++mf) {
        #pragma unroll
        for (int j = 0; j < 4; ++j) {
            int m = m0 + mf * 16 + lg * 4 + j;
            float* po = outf + (size_t)m * 1024 + n0 + wn * 32 + l15;
            po[0]  = acc[mf][0][j] + bv[0];
            po[16] = acc[mf][1][j] + bv[1];
        }
    }
}

// ---------------- causal flash attention (16x16, 8 waves, reg-P) ----------------
__global__ __launch_bounds__(512) void k_attn(
    const _Float16* __restrict__ qkv,   // natural (Q cols 0..1023, K cols 1024..2047 pre-scaled)
    const _Float16* __restrict__ VTg,   // [bh][d][2048] kappa-permuted
    _Float16* __restrict__ Y)
{
    __shared__ _Float16 Kt[128 * 64];    // [k][d], 16B slots XOR (k&7)
    __shared__ _Float16 Vt[64 * 128];    // [d][p], 16B slots XOR (d&15)

    const int tid  = threadIdx.x;
    const int lane = tid & 63;
    const int w    = tid >> 6;           // 0..7 (q-row block)
    const int l15  = lane & 15;
    const int lg   = lane >> 4;
    const int bh   = blockIdx.x;
    const int by   = blockIdx.y;
    const int qt   = (by < 8) ? (15 - by) : (by - 8);   // pairs sum to 17 tiles
    const int b    = bh >> 4, h = bh & 15;

    const int rA  = tid >> 3;
    const int slA = tid & 7;
    const size_t kOffA = (size_t)rA * 3072 + ((slA ^ (rA & 7)) * 8);
    const _Float16* kBase = qkv + (size_t)(b * 2048) * 3072 + 1024 + h * 64;

    const int dA = tid >> 4;
    const int sA = tid & 15;
    const size_t vOffA = (size_t)dA * 2048 + ((sA ^ (dA & 15)) * 8);
    const _Float16* vBase = VTg + (size_t)bh * TSEQ * HD;

    const int x7   = l15 & 7;
    const int kph0 = (lg ^ x7) * 8;
    const int kph1 = ((4 + lg) ^ x7) * 8;

    const int qrow = qt * 128 + w * 16 + l15;
    const _Float16* qptr = qkv + (size_t)(b * 2048 + qrow) * 3072 + h * 64;
    half8 qa0 = *(const half8*)&qptr[lg * 8];
    half8 qa1 = *(const half8*)&qptr[32 + lg * 8];

    half8 ones;
    #pragma unroll
    for (int i = 0; i < 8; ++i) ones[i] = (_Float16)1.0f;

    f32x4 yac[4];
    #pragma unroll
    for (int nf = 0; nf < 4; ++nf) yac[nf] = (f32x4){0.f, 0.f, 0.f, 0.f};
    f32x4 lsum = (f32x4){0.f, 0.f, 0.f, 0.f};

    const int nkt = qt + 1;

    half8 kra = *(const half8*)(kBase + kOffA);
    half8 krb = *(const half8*)(kBase + kOffA + (size_t)64 * 3072);
    half8 vra = *(const half8*)(vBase + vOffA);
    half8 vrb = *(const half8*)(vBase + vOffA + 32 * 2048);

    for (int kt = 0; kt < nkt; ++kt) {
        __syncthreads();
        *(half8*)&Kt[tid * 8]        = kra;
        *(half8*)&Kt[4096 + tid * 8] = krb;
        *(half8*)&Vt[tid * 8]        = vra;
        *(half8*)&Vt[4096 + tid * 8] = vrb;
        if (kt + 1 < nkt) {
            const _Float16* kp = kBase + (size_t)(kt + 1) * 128 * 3072;
            kra = *(const half8*)(kp + kOffA);
            krb = *(const half8*)(kp + kOffA + (size_t)64 * 3072);
            const _Float16* vp = vBase + (kt + 1) * 128;
            vra = *(const half8*)(vp + vOffA);
            vrb = *(const half8*)(vp + vOffA + 32 * 2048);
        }
        __syncthreads();

        const bool diag = (kt == nkt - 1);

        // S^T = K Q^T : lane (q=l15, lg) holds S[q][k], k = 16f + 4lg + j
        f32x4 s[8];
        __builtin_amdgcn_s_setprio(1);
        #pragma unroll
        for (int f = 0; f < 8; ++f) {
            if (diag && f > w) { s[f] = (f32x4){0.f, 0.f, 0.f, 0.f}; continue; }
            int rr = f * 16 + l15;
            half8 kb0 = *(const half8*)&Kt[rr * 64 + kph0];
            half8 kb1 = *(const half8*)&Kt[rr * 64 + kph1];
            f32x4 z = (f32x4){0.f, 0.f, 0.f, 0.f};
            z = __builtin_amdgcn_mfma_f32_16x16x32_f16(kb0, qa0, z, 0, 0, 0);
            z = __builtin_amdgcn_mfma_f32_16x16x32_f16(kb1, qa1, z, 0, 0, 0);
            s[f] = z;
        }
        __builtin_amdgcn_s_setprio(0);

        if (diag) {
            const int qg = qt * 128 + w * 16 + l15;
            #pragma unroll
            for (int f = 0; f < 8; ++f) {
                if (f > w) continue;
                #pragma unroll
                for (int j = 0; j < 4; ++j) {
                    int kk = kt * 128 + 16 * f + 4 * lg + j;
                    s[f][j] = (kk > qg) ? 0.f : exp2f(s[f][j]);
                }
            }
        } else {
            #pragma unroll
            for (int f = 0; f < 8; ++f)
                #pragma unroll
                for (int j = 0; j < 4; ++j) s[f][j] = exp2f(s[f][j]);
        }

        __builtin_amdgcn_s_setprio(1);
        #pragma unroll
        for (int t = 0; t < 4; ++t) {
            int4v pi;
            pi[0] = pk2(s[2 * t][0],     s[2 * t][1]);
            pi[1] = pk2(s[2 * t][2],     s[2 * t][3]);
            pi[2] = pk2(s[2 * t + 1][0], s[2 * t + 1][1]);
            pi[3] = pk2(s[2 * t + 1][2], s[2 * t + 1][3]);
            half8 pa = __builtin_bit_cast(half8, pi);
            lsum = __builtin_amdgcn_mfma_f32_16x16x32_f16(pa, ones, lsum, 0, 0, 0);
            #pragma unroll
            for (int nf = 0; nf < 4; ++nf) {
                half8 vb = *(const half8*)&Vt[(nf * 16 + l15) * 128 + (((t * 4 + lg) ^ l15) * 8)];
                yac[nf] = __builtin_amdgcn_mfma_f32_16x16x32_f16(pa, vb, yac[nf], 0, 0, 0);
            }
        }
        __builtin_amdgcn_s_setprio(0);
    }

    const int trow = qt * 128 + w * 16 + lg * 4;
    #pragma unroll
    for (int j = 0; j < 4; ++j) {
        float inv = 1.f / lsum[j];
        #pragma unroll
        for (int nf = 0; nf < 4; ++nf) {
            float yv = yac[nf][j] * inv;
            Y[((size_t)b * TSEQ + trow + j) * EMBD + h * 64 + nf * 16 + l15] = (_Float16)yv;
        }
    }
}

// ---------------- launch ----------------
extern "C" void kernel_launch(void* const* d_in, const int* in_sizes, int n_in,
                              void* d_out, int out_size, void* d_ws, size_t ws_size,
                              hipStream_t stream) {
    const float* x  = (const float*)d_in[0];
    const float* Wa = (const float*)d_in[1];
    const float* ba = (const float*)d_in[2];
    const float* Wp = (const float*)d_in[3];
    const float* bp = (const float*)d_in[4];
    float* out = (float*)d_out;

    _Float16* Xh   = (_Float16*)d_ws;                  // 4096x1024 (aliased by Yh later)
    _Float16* WaT  = Xh   + (size_t)4096 * 1024;       // 3072x1024
    _Float16* WpT  = WaT  + (size_t)3072 * 1024;       // 1024x1024
    _Float16* QKVn = WpT  + (size_t)1024 * 1024;       // 4096x3072 (V region unused)
    _Float16* VTb  = QKVn + (size_t)4096 * 3072;       // 32x64x2048 kappa-permuted
    _Float16* Yh   = Xh;                               // alias: Xh dead after GEMM1

    k_prep<<<8192, 256, 0, stream>>>(x, Xh, Wa, Wp, WaT, WpT);

    k_gemm_qkv<<<1536, 256, 0, stream>>>(Xh, WaT, ba, QKVn, VTb);

    k_attn<<<dim3(NBH, 16), 512, 0, stream>>>(QKVn, VTb, Yh);

    k_gemm_proj<<<512, 256, 0, stream>>>(Yh, WpT, bp, out);
}

// Round 13
// 95.945 us; speedup vs baseline: 1.2008x; 1.0114x over previous
//
#include <hip/hip_runtime.h>
#include <cstdint>
#include <cstddef>

typedef _Float16 half8 __attribute__((ext_vector_type(8)));
typedef _Float16 half4v __attribute__((ext_vector_type(4)));
typedef float f32x4 __attribute__((ext_vector_type(4)));
typedef int int4v __attribute__((ext_vector_type(4)));

#define EMBD 1024
#define NHEAD 16
#define TSEQ 2048
#define NB 2
#define HD 64
#define NBH (NB*NHEAD)          // 32
#define SCK 0.18033688f         // 0.125 * log2(e)

static __device__ __forceinline__ void gload_lds16(const void* g, void* l) {
    __builtin_amdgcn_global_load_lds((const __attribute__((address_space(1))) void*)g,
                                     (__attribute__((address_space(3))) void*)l,
                                     16, 0, 0);
}

static __device__ __forceinline__ int pk2(float a, float b) {
    return __builtin_bit_cast(int, __builtin_amdgcn_cvt_pkrtz(a, b));
}

// ---------------- fused prep: x fp32->fp16 convert + both W transposes ----------------
__global__ __launch_bounds__(256) void k_prep(
    const float* __restrict__ x,  _Float16* __restrict__ xh,
    const float* __restrict__ Wa, const float* __restrict__ Wp,
    _Float16* __restrict__ WaT,   _Float16* __restrict__ WpT)
{
    const int bx = blockIdx.x;
    if (bx < 4096) {
        int i = bx * 256 + threadIdx.x;
        float4 v = ((const float4*)x)[i];
        half4v h;
        h.x = (_Float16)v.x; h.y = (_Float16)v.y; h.z = (_Float16)v.z; h.w = (_Float16)v.w;
        ((half4v*)xh)[i] = h;
        return;
    }
    __shared__ float tile[32][33];
    const int idx = bx - 4096;          // 0..4095
    const int bxx = idx & 127;          // 0..127 (96 Wa + 32 Wp)
    const int byy = idx >> 7;           // 0..31
    const bool isA = bxx < 96;
    const float* in  = isA ? Wa : Wp;
    _Float16* out    = isA ? WaT : WpT;
    const int C      = isA ? 3072 : 1024;
    const int c0 = (isA ? bxx : bxx - 96) * 32, r0 = byy * 32;
    const int tx = threadIdx.x & 31, ty = threadIdx.x >> 5;   // 32 x 8
    #pragma unroll
    for (int j = 0; j < 4; ++j)
        tile[ty + 8*j][tx] = in[(size_t)(r0 + ty + 8*j) * C + c0 + tx];
    __syncthreads();
    #pragma unroll
    for (int j = 0; j < 4; ++j)
        out[(size_t)(c0 + ty + 8*j) * 1024 + r0 + tx] = (_Float16)tile[tx][ty + 8*j];
}

// ---------------- QKV GEMM: 128x64 tile (1536 blocks -> ~6/CU) ----------------
__global__ __launch_bounds__(256) void k_gemm_qkv(
    const _Float16* __restrict__ A,     // [4096][1024]
    const _Float16* __restrict__ Bt,    // [3072][1024]
    const float* __restrict__ bias,     // [3072]
    _Float16* __restrict__ outq,        // [4096][3072] (V region unused)
    _Float16* __restrict__ VT)          // [32][64][2048]
{
    __shared__ _Float16 smem[12288];    // As[0:8192) 128x64, Bs[8192:12288) 64x64
    _Float16* As = smem;
    _Float16* Bs = smem + 8192;

    const int d    = blockIdx.x;               // 0..1535
    const int xcd  = d & 7;
    const int idx  = d >> 3;                   // 0..191
    const int mt   = (xcd >> 1) * 8  + (idx & 7);
    const int ntl  = (xcd &  1) * 24 + (idx >> 3);
    const int m0 = mt * 128, n0 = ntl * 64;

    const int tid  = threadIdx.x;
    const int lane = tid & 63;
    const int w    = tid >> 6;
    const int wm   = w >> 1, wn = w & 1;       // wave: 64m x 32n
    const int l15  = lane & 15;
    const int lg   = lane >> 4;

    f32x4 acc[4][2];
    #pragma unroll
    for (int i = 0; i < 4; ++i) {
        acc[i][0] = (f32x4){0.f, 0.f, 0.f, 0.f};
        acc[i][1] = (f32x4){0.f, 0.f, 0.f, 0.f};
    }

    for (int kt = 0; kt < 16; ++kt) {
        __syncthreads();
        #pragma unroll
        for (int c = 0; c < 4; ++c) {          // A: 1024 segs
            int s = c * 256 + tid;
            int r = s >> 3, sl = s & 7;
            const _Float16* ga = A + (size_t)(m0 + r) * 1024 + kt * 64 + ((sl ^ (r & 7)) * 8);
            gload_lds16(ga, (char*)As + s * 16);
        }
        #pragma unroll
        for (int c = 0; c < 2; ++c) {          // B: 512 segs
            int s = c * 256 + tid;
            int r = s >> 3, sl = s & 7;
            const _Float16* gb = Bt + (size_t)(n0 + r) * 1024 + kt * 64 + ((sl ^ (r & 7)) * 8);
            gload_lds16(gb, (char*)Bs + s * 16);
        }
        __syncthreads();

        half8 af[4][2], bf[2][2];
        #pragma unroll
        for (int mf = 0; mf < 4; ++mf) {
            int r = wm * 64 + mf * 16 + l15;
            #pragma unroll
            for (int ks = 0; ks < 2; ++ks)
                af[mf][ks] = *(const half8*)((const char*)As + r * 128 + (((ks * 4 + lg) ^ (r & 7)) * 16));
        }
        #pragma unroll
        for (int nf = 0; nf < 2; ++nf) {
            int r = wn * 32 + nf * 16 + l15;
            #pragma unroll
            for (int ks = 0; ks < 2; ++ks)
                bf[nf][ks] = *(const half8*)((const char*)Bs + r * 128 + (((ks * 4 + lg) ^ (r & 7)) * 16));
        }
        #pragma unroll
        for (int mf = 0; mf < 4; ++mf)
            #pragma unroll
            for (int nf = 0; nf < 2; ++nf) {
                acc[mf][nf] = __builtin_amdgcn_mfma_f32_16x16x32_f16(af[mf][0], bf[nf][0], acc[mf][nf], 0, 0, 0);
                acc[mf][nf] = __builtin_amdgcn_mfma_f32_16x16x32_f16(af[mf][1], bf[nf][1], acc[mf][nf], 0, 0, 0);
            }
    }

    float bv[2];
    bv[0] = bias[n0 + wn * 32 + l15];
    bv[1] = bias[n0 + wn * 32 + 16 + l15];

    const int which = n0 >> 10;         // 0=Q, 1=K, 2=V
    if (which < 2) {
        const float osc = (which == 1) ? SCK : 1.0f;
        #pragma unroll
        for (int mf = 0; mf < 4; ++mf) {
            #pragma unroll
            for (int j = 0; j < 4; ++j) {
                int m = m0 + wm * 64 + mf * 16 + lg * 4 + j;
                _Float16* po = outq + (size_t)m * 3072 + n0 + wn * 32 + l15;
                po[0]  = (_Float16)((acc[mf][0][j] + bv[0]) * osc);
                po[16] = (_Float16)((acc[mf][1][j] + bv[1]) * osc);
            }
        }
    } else {
        // ---- V: transpose through LDS (tile[128 t][65-stride d]), write VT ----
        __syncthreads();
        #pragma unroll
        for (int mf = 0; mf < 4; ++mf)
            #pragma unroll
            for (int j = 0; j < 4; ++j) {
                int m = wm * 64 + mf * 16 + lg * 4 + j;       // t_local
                smem[m * 65 + wn * 32 + l15]      = (_Float16)(acc[mf][0][j] + bv[0]);
                smem[m * 65 + wn * 32 + 16 + l15] = (_Float16)(acc[mf][1][j] + bv[1]);
            }
        __syncthreads();

        const int b     = m0 >> 11;
        const int h     = (n0 - 2048) >> 6;
        const int tloc0 = m0 & 2047;
        _Float16* vbase = VT + ((size_t)(b * 16 + h) * 64) * 2048 + tloc0;
        #pragma unroll
        for (int c = 0; c < 4; ++c) {
            int seg = c * 256 + tid;           // 0..1023
            int dd  = seg >> 4;                // 0..63
            int s   = seg & 15;                // 16B segment
            half8 hv8;
            #pragma unroll
            for (int e = 0; e < 8; ++e) {
                int p = s * 8 + e;
                int k = 16 * (2 * (p >> 5) + ((p & 7) >> 2)) + 4 * ((p >> 3) & 3) + (p & 3);
                hv8[e] = smem[k * 65 + dd];
            }
            *(half8*)&vbase[(size_t)dd * 2048 + s * 8] = hv8;
        }
    }
}

// ---------------- proj GEMM: 64x128 tile, 2D XCD chunks ----------------
__global__ __launch_bounds__(256) void k_gemm_proj(
    const _Float16* __restrict__ A,     // [4096][1024] (Y)
    const _Float16* __restrict__ Bt,    // [1024][1024] (WpT)
    const float* __restrict__ bias,     // [1024]
    float* __restrict__ outf)           // [4096][1024]
{
    __shared__ _Float16 As[64 * 64];    // 8 KB
    __shared__ _Float16 Bs[128 * 64];   // 16 KB

    const int d   = blockIdx.x;                 // 0..511
    const int xcd = d & 7;
    const int idx = d >> 3;                     // 0..63
    const int mt  = (xcd >> 1) * 16 + (idx & 15);
    const int nt  = (xcd &  1) * 4  + (idx >> 4);
    const int m0 = mt * 64, n0 = nt * 128;

    const int tid  = threadIdx.x;
    const int lane = tid & 63;
    const int wn   = tid >> 6;                  // wave 0..3 = n-slice
    const int l15  = lane & 15;
    const int lg   = lane >> 4;

    f32x4 acc[4][2];
    #pragma unroll
    for (int i = 0; i < 4; ++i) {
        acc[i][0] = (f32x4){0.f, 0.f, 0.f, 0.f};
        acc[i][1] = (f32x4){0.f, 0.f, 0.f, 0.f};
    }

    for (int kt = 0; kt < 16; ++kt) {
        __syncthreads();
        #pragma unroll
        for (int c = 0; c < 2; ++c) {
            int s = c * 256 + tid;
            int r = s >> 3, sl = s & 7;
            const _Float16* ga = A + (size_t)(m0 + r) * 1024 + kt * 64 + ((sl ^ (r & 7)) * 8);
            gload_lds16(ga, (char*)As + s * 16);
        }
        #pragma unroll
        for (int c = 0; c < 4; ++c) {
            int s = c * 256 + tid;
            int r = s >> 3, sl = s & 7;
            const _Float16* gb = Bt + (size_t)(n0 + r) * 1024 + kt * 64 + ((sl ^ (r & 7)) * 8);
            gload_lds16(gb, (char*)Bs + s * 16);
        }
        __syncthreads();

        half8 af[4][2], bf[2][2];
        #pragma unroll
        for (int mf = 0; mf < 4; ++mf) {
            int r = mf * 16 + l15;
            #pragma unroll
            for (int ks = 0; ks < 2; ++ks)
                af[mf][ks] = *(const half8*)((const char*)As + r * 128 + (((ks * 4 + lg) ^ (r & 7)) * 16));
        }
        #pragma unroll
        for (int nf = 0; nf < 2; ++nf) {
            int r = wn * 32 + nf * 16 + l15;
            #pragma unroll
            for (int ks = 0; ks < 2; ++ks)
                bf[nf][ks] = *(const half8*)((const char*)Bs + r * 128 + (((ks * 4 + lg) ^ (r & 7)) * 16));
        }
        #pragma unroll
        for (int mf = 0; mf < 4; ++mf)
            #pragma unroll
            for (int nf = 0; nf < 2; ++nf) {
                acc[mf][nf] = __builtin_amdgcn_mfma_f32_16x16x32_f16(af[mf][0], bf[nf][0], acc[mf][nf], 0, 0, 0);
                acc[mf][nf] = __builtin_amdgcn_mfma_f32_16x16x32_f16(af[mf][1], bf[nf][1], acc[mf][nf], 0, 0, 0);
            }
    }

    float bv[2];
    bv[0] = bias[n0 + wn * 32 + l15];
    bv[1] = bias[n0 + wn * 32 + 16 + l15];

    #pragma unroll
    for (int mf = 0; mf < 4; ++mf) {
        #pragma unroll
        for (int j = 0; j < 4; ++j) {
            int m = m0 + mf * 16 + lg * 4 + j;
            float* po = outf + (size_t)m * 1024 + n0 + wn * 32 + l15;
            po[0]  = acc[mf][0][j] + bv[0];
            po[16] = acc[mf][1][j] + bv[1];
        }
    }
}

// ---------------- causal flash attention (16x16, 8 waves, reg-P, LDS dbuf) ----------------
// Double-buffered K/V tiles; ONE raw s_barrier per tile with lgkmcnt(0) only —
// next-tile global loads stay in flight across the barrier (no vmcnt drain).
__global__ __launch_bounds__(512) void k_attn(
    const _Float16* __restrict__ qkv,   // natural (Q cols 0..1023, K cols 1024..2047 pre-scaled)
    const _Float16* __restrict__ VTg,   // [bh][d][2048] kappa-permuted
    _Float16* __restrict__ Y)
{
    __shared__ _Float16 Kt[2][8192];    // [k][d], 16B slots XOR (k&7)
    __shared__ _Float16 Vt[2][8192];    // [d][p], 16B slots XOR (d&15)

    const int tid  = threadIdx.x;
    const int lane = tid & 63;
    const int w    = tid >> 6;           // 0..7 (q-row block)
    const int l15  = lane & 15;
    const int lg   = lane >> 4;
    const int bh   = blockIdx.x;
    const int by   = blockIdx.y;
    const int qt   = (by < 8) ? (15 - by) : (by - 8);   // pairs sum to 17 tiles
    const int b    = bh >> 4, h = bh & 15;

    const int rA  = tid >> 3;
    const int slA = tid & 7;
    const size_t kOffA = (size_t)rA * 3072 + ((slA ^ (rA & 7)) * 8);
    const _Float16* kBase = qkv + (size_t)(b * 2048) * 3072 + 1024 + h * 64;

    const int dA = tid >> 4;
    const int sA = tid & 15;
    const size_t vOffA = (size_t)dA * 2048 + ((sA ^ (dA & 15)) * 8);
    const _Float16* vBase = VTg + (size_t)bh * TSEQ * HD;

    const int x7   = l15 & 7;
    const int kph0 = (lg ^ x7) * 8;
    const int kph1 = ((4 + lg) ^ x7) * 8;

    const int qrow = qt * 128 + w * 16 + l15;
    const _Float16* qptr = qkv + (size_t)(b * 2048 + qrow) * 3072 + h * 64;
    half8 qa0 = *(const half8*)&qptr[lg * 8];
    half8 qa1 = *(const half8*)&qptr[32 + lg * 8];

    half8 ones;
    #pragma unroll
    for (int i = 0; i < 8; ++i) ones[i] = (_Float16)1.0f;

    f32x4 yac[4];
    #pragma unroll
    for (int nf = 0; nf < 4; ++nf) yac[nf] = (f32x4){0.f, 0.f, 0.f, 0.f};
    f32x4 lsum = (f32x4){0.f, 0.f, 0.f, 0.f};

    const int nkt = qt + 1;

    // prologue: tile 0 into regs
    half8 kra = *(const half8*)(kBase + kOffA);
    half8 krb = *(const half8*)(kBase + kOffA + (size_t)64 * 3072);
    half8 vra = *(const half8*)(vBase + vOffA);
    half8 vrb = *(const half8*)(vBase + vOffA + 32 * 2048);

    for (int kt = 0; kt < nkt; ++kt) {
        const int cur = kt & 1;
        _Float16* KtC = Kt[cur];
        _Float16* VtC = Vt[cur];
        // write staged regs -> buf cur (last read two barriers ago; laggard
        // waves sit between consecutive barriers reading buf cur^1 - disjoint)
        *(half8*)&KtC[tid * 8]        = kra;
        *(half8*)&KtC[4096 + tid * 8] = krb;
        *(half8*)&VtC[tid * 8]        = vra;
        *(half8*)&VtC[4096 + tid * 8] = vrb;
        if (kt + 1 < nkt) {                    // issue next-tile loads; they stay
            const _Float16* kp = kBase + (size_t)(kt + 1) * 128 * 3072;   // in flight
            kra = *(const half8*)(kp + kOffA);                            // across the
            krb = *(const half8*)(kp + kOffA + (size_t)64 * 3072);        // barrier
            const _Float16* vp = vBase + (kt + 1) * 128;
            vra = *(const half8*)(vp + vOffA);
            vrb = *(const half8*)(vp + vOffA + 32 * 2048);
        }
        asm volatile("s_waitcnt lgkmcnt(0)" ::: "memory");   // ds_writes visible; vmcnt NOT drained
        __builtin_amdgcn_s_barrier();
        __builtin_amdgcn_sched_barrier(0);

        const bool diag = (kt == nkt - 1);

        // S^T = K Q^T : lane (q=l15, lg) holds S[q][k], k = 16f + 4lg + j
        f32x4 s[8];
        __builtin_amdgcn_s_setprio(1);
        #pragma unroll
        for (int f = 0; f < 8; ++f) {
            if (diag && f > w) { s[f] = (f32x4){0.f, 0.f, 0.f, 0.f}; continue; }
            int rr = f * 16 + l15;
            half8 kb0 = *(const half8*)&KtC[rr * 64 + kph0];
            half8 kb1 = *(const half8*)&KtC[rr * 64 + kph1];
            f32x4 z = (f32x4){0.f, 0.f, 0.f, 0.f};
            z = __builtin_amdgcn_mfma_f32_16x16x32_f16(kb0, qa0, z, 0, 0, 0);
            z = __builtin_amdgcn_mfma_f32_16x16x32_f16(kb1, qa1, z, 0, 0, 0);
            s[f] = z;
        }
        __builtin_amdgcn_s_setprio(0);

        if (diag) {
            const int qg = qt * 128 + w * 16 + l15;
            #pragma unroll
            for (int f = 0; f < 8; ++f) {
                if (f > w) continue;
                #pragma unroll
                for (int j = 0; j < 4; ++j) {
                    int kk = kt * 128 + 16 * f + 4 * lg + j;
                    s[f][j] = (kk > qg) ? 0.f : exp2f(s[f][j]);
                }
            }
        } else {
            #pragma unroll
            for (int f = 0; f < 8; ++f)
                #pragma unroll
                for (int j = 0; j < 4; ++j) s[f][j] = exp2f(s[f][j]);
        }

        __builtin_amdgcn_s_setprio(1);
        #pragma unroll
        for (int t = 0; t < 4; ++t) {
            int4v pi;
            pi[0] = pk2(s[2 * t][0],     s[2 * t][1]);
            pi[1] = pk2(s[2 * t][2],     s[2 * t][3]);
            pi[2] = pk2(s[2 * t + 1][0], s[2 * t + 1][1]);
            pi[3] = pk2(s[2 * t + 1][2], s[2 * t + 1][3]);
            half8 pa = __builtin_bit_cast(half8, pi);
            lsum = __builtin_amdgcn_mfma_f32_16x16x32_f16(pa, ones, lsum, 0, 0, 0);
            #pragma unroll
            for (int nf = 0; nf < 4; ++nf) {
                half8 vb = *(const half8*)&VtC[(nf * 16 + l15) * 128 + (((t * 4 + lg) ^ l15) * 8)];
                yac[nf] = __builtin_amdgcn_mfma_f32_16x16x32_f16(pa, vb, yac[nf], 0, 0, 0);
            }
        }
        __builtin_amdgcn_s_setprio(0);
    }

    const int trow = qt * 128 + w * 16 + lg * 4;
    #pragma unroll
    for (int j = 0; j < 4; ++j) {
        float inv = 1.f / lsum[j];
        #pragma unroll
        for (int nf = 0; nf < 4; ++nf) {
            float yv = yac[nf][j] * inv;
            Y[((size_t)b * TSEQ + trow + j) * EMBD + h * 64 + nf * 16 + l15] = (_Float16)yv;
        }
    }
}

// ---------------- launch ----------------
extern "C" void kernel_launch(void* const* d_in, const int* in_sizes, int n_in,
                              void* d_out, int out_size, void* d_ws, size_t ws_size,
                              hipStream_t stream) {
    const float* x  = (const float*)d_in[0];
    const float* Wa = (const float*)d_in[1];
    const float* ba = (const float*)d_in[2];
    const float* Wp = (const float*)d_in[3];
    const float* bp = (const float*)d_in[4];
    float* out = (float*)d_out;

    _Float16* Xh   = (_Float16*)d_ws;                  // 4096x1024 (aliased by Yh later)
    _Float16* WaT  = Xh   + (size_t)4096 * 1024;       // 3072x1024
    _Float16* WpT  = WaT  + (size_t)3072 * 1024;       // 1024x1024
    _Float16* QKVn = WpT  + (size_t)1024 * 1024;       // 4096x3072 (V region unused)
    _Float16* VTb  = QKVn + (size_t)4096 * 3072;       // 32x64x2048 kappa-permuted
    _Float16* Yh   = Xh;                               // alias: Xh dead after GEMM1

    k_prep<<<8192, 256, 0, stream>>>(x, Xh, Wa, Wp, WaT, WpT);

    k_gemm_qkv<<<1536, 256, 0, stream>>>(Xh, WaT, ba, QKVn, VTb);

    k_attn<<<dim3(NBH, 16), 512, 0, stream>>>(QKVn, VTb, Yh);

    k_gemm_proj<<<512, 256, 0, stream>>>(Yh, WpT, bp, out);
}